// Round 6
// baseline (619.970 us; speedup 1.0000x reference)
//
#include <hip/hip_runtime.h>

#define EPSV 1e-5f

// Problem constants: B=4, N=8, B2=32, C=128, H=W=64, HW=4096, KS=3
// Workspace (floats): k2d@0 (16777216), v@16777216 (16777216), wd@33554432 (12582912),
// stats@46137344: gnsum[1024] gnsq[1024] gap[512] gnmean[1024] gnrstd[1024] attn[1024]

__device__ __forceinline__ void block_sum_atomic(float val, float* dst) {
    __shared__ float sm[4];
    #pragma unroll
    for (int off = 32; off; off >>= 1) val += __shfl_down(val, off, 64);
    int lane = threadIdx.x & 63, wid = threadIdx.x >> 6;
    if (lane == 0) sm[wid] = val;
    __syncthreads();
    if (threadIdx.x == 0) atomicAdd(dst, sm[0] + sm[1] + sm[2] + sm[3]);
}

__device__ __forceinline__ unsigned bfbits(float f) {   // RNE f32->bf16 bits
    unsigned u = __float_as_uint(f);
    u += 0x7fff + ((u >> 16) & 1);
    return u >> 16;
}

// ---- kA: key_embed = ReLU(BN(grouped temporal conv3d)) + gap partial ----
__global__ __launch_bounds__(256, 4) void kA_key(
    const float* __restrict__ x, const float* __restrict__ wk,
    const float* __restrict__ g, const float* __restrict__ bb,
    const float* __restrict__ m, const float* __restrict__ vr,
    float* __restrict__ k2d, float* __restrict__ gap)
{
    int blk   = blockIdx.x;
    int strip = blk & 3;
    int half  = (blk >> 2) & 1;
    int grp   = (blk >> 3) & 3;
    int b2    = blk >> 5;
    int px0   = strip * 1024 + threadIdx.x * 4;
    int bi = b2 >> 3, ni = b2 & 7;
    int gch = grp * 32;
    int ob  = gch + half * 16;

    float acc[16][4];
    #pragma unroll
    for (int j = 0; j < 16; ++j)
        acc[j][0] = acc[j][1] = acc[j][2] = acc[j][3] = 0.f;

    #pragma unroll
    for (int dk = 0; dk < 3; ++dk) {
        int nf = ni + dk - 1;
        if (nf >= 0 && nf < 8) {
            const float* xp  = x + ((bi * 8 + nf) * 128 + gch) * 4096 + px0;
            const float* wkp = wk + ob * 96 + dk;
            #pragma unroll 4
            for (int ci = 0; ci < 32; ++ci) {
                const float4 xv = *(const float4*)(xp + ci * 4096);
                #pragma unroll
                for (int j = 0; j < 16; ++j) {
                    float wv = wkp[j * 96 + ci * 3];
                    acc[j][0] = fmaf(xv.x, wv, acc[j][0]);
                    acc[j][1] = fmaf(xv.y, wv, acc[j][1]);
                    acc[j][2] = fmaf(xv.z, wv, acc[j][2]);
                    acc[j][3] = fmaf(xv.w, wv, acc[j][3]);
                }
            }
        }
    }

    int lane = threadIdx.x & 63, wid = threadIdx.x >> 6;
    __shared__ float ssum[16][4];
    #pragma unroll
    for (int j = 0; j < 16; ++j) {
        int o = ob + j;
        float s = g[o] * rsqrtf(vr[o] + EPSV);
        float t = bb[o] - m[o] * s;
        float4 r;
        r.x = fmaxf(fmaf(acc[j][0], s, t), 0.f);
        r.y = fmaxf(fmaf(acc[j][1], s, t), 0.f);
        r.z = fmaxf(fmaf(acc[j][2], s, t), 0.f);
        r.w = fmaxf(fmaf(acc[j][3], s, t), 0.f);
        *(float4*)(k2d + (b2 * 128 + o) * 4096 + px0) = r;
        float lsum = r.x + r.y + r.z + r.w;
        #pragma unroll
        for (int off = 32; off; off >>= 1) lsum += __shfl_down(lsum, off, 64);
        if (lane == 0) ssum[j][wid] = lsum;
    }
    __syncthreads();
    if (threadIdx.x < 16) {
        float* sr = ssum[threadIdx.x];
        atomicAdd(&gap[bi * 128 + ob + threadIdx.x], sr[0] + sr[1] + sr[2] + sr[3]);
    }
}

// ---- kB: v = BN(x @ w_1x1); 16 oc x 1024-px strip; thread = 4 px ----
__global__ __launch_bounds__(256, 4) void kB_val(
    const float* __restrict__ x, const float* __restrict__ w,
    const float* __restrict__ g, const float* __restrict__ bb,
    const float* __restrict__ m, const float* __restrict__ vr,
    float* __restrict__ vout)
{
    int blk   = blockIdx.x;
    int ocg   = blk & 7;
    int strip = (blk >> 3) & 3;
    int b2    = blk >> 5;
    int px0   = strip * 1024 + threadIdx.x * 4;
    const float* xp = x + b2 * 128 * 4096 + px0;
    const float* wp = w + ocg * 16 * 128;

    float acc[16][4];
    #pragma unroll
    for (int j = 0; j < 16; ++j)
        acc[j][0] = acc[j][1] = acc[j][2] = acc[j][3] = 0.f;

    #pragma unroll 4
    for (int c = 0; c < 128; ++c) {
        const float4 xv = *(const float4*)(xp + c * 4096);
        #pragma unroll
        for (int j = 0; j < 16; ++j) {
            float wv = wp[j * 128 + c];
            acc[j][0] = fmaf(xv.x, wv, acc[j][0]);
            acc[j][1] = fmaf(xv.y, wv, acc[j][1]);
            acc[j][2] = fmaf(xv.z, wv, acc[j][2]);
            acc[j][3] = fmaf(xv.w, wv, acc[j][3]);
        }
    }
    #pragma unroll
    for (int j = 0; j < 16; ++j) {
        int o = ocg * 16 + j;
        float s = g[o] * rsqrtf(vr[o] + EPSV);
        float t = bb[o] - m[o] * s;
        float4 r;
        r.x = fmaf(acc[j][0], s, t);
        r.y = fmaf(acc[j][1], s, t);
        r.z = fmaf(acc[j][2], s, t);
        r.w = fmaf(acc[j][3], s, t);
        *(float4*)(vout + (b2 * 128 + o) * 4096 + px0) = r;
    }
}

// ---- kC: e = ReLU(BN([x;k2d]@w_e1)), wd = e@w_e2+b, GN partials ----
// Block = 64 px (1 px/thread); wave q: e-ch [16q,16q+16), wd rows [24q,24q+24).
// Grid 2048 -> 8 blocks/CU; LDS e-exchange bf16 [64][64] = 8 KB.
__global__ __launch_bounds__(256, 8) void kC_wd(
    const float* __restrict__ x, const float* __restrict__ k2d,
    const float* __restrict__ we1,
    const float* __restrict__ eg, const float* __restrict__ eb,
    const float* __restrict__ em, const float* __restrict__ ev,
    const float* __restrict__ we2, const float* __restrict__ be2,
    float* __restrict__ wd, float* __restrict__ gnsum, float* __restrict__ gnsq)
{
    int tid  = threadIdx.x;
    int lane = tid & 63;
    int q    = __builtin_amdgcn_readfirstlane(tid >> 6);
    int tile = blockIdx.x & 63;
    int b2   = blockIdx.x >> 6;
    int px0  = tile * 64 + lane;

    const float* xp  = x   + b2 * 128 * 4096 + px0;
    const float* kp  = k2d + b2 * 128 * 4096 + px0;
    const float* w1q = we1 + q * 16 * 256;

    float acc[16];
    #pragma unroll
    for (int j = 0; j < 16; ++j) acc[j] = 0.f;

    #pragma unroll 4
    for (int c = 0; c < 128; ++c) {
        float xv = xp[c * 4096];
        float kv = kp[c * 4096];
        #pragma unroll
        for (int j = 0; j < 16; ++j)
            acc[j] = fmaf(xv, w1q[j * 256 + c], acc[j]);
        #pragma unroll
        for (int j = 0; j < 16; ++j)
            acc[j] = fmaf(kv, w1q[j * 256 + 128 + c], acc[j]);
    }

    __shared__ unsigned short e_s[64][64];   // bf16 bits, 8 KB
    #pragma unroll
    for (int j = 0; j < 16; ++j) {
        int eo = q * 16 + j;
        float s = eg[eo] * rsqrtf(ev[eo] + EPSV);
        float t = eb[eo] - em[eo] * s;
        float r = fmaxf(fmaf(acc[j], s, t), 0.f);
        e_s[eo][lane] = (unsigned short)bfbits(r);
    }
    __syncthreads();

    float wa[24];
    const float* w2q = we2 + q * 24 * 64;
    #pragma unroll
    for (int j = 0; j < 24; ++j) wa[j] = be2[q * 24 + j];
    #pragma unroll 4
    for (int c = 0; c < 64; ++c) {
        float evv = __uint_as_float(((unsigned)e_s[c][lane]) << 16);
        #pragma unroll
        for (int j = 0; j < 24; ++j)
            wa[j] = fmaf(evv, w2q[j * 64 + c], wa[j]);
    }

    float* wdp = wd + (b2 * 96 + q * 24) * 4096 + px0;
    #pragma unroll
    for (int j = 0; j < 24; ++j)
        wdp[j * 4096] = wa[j];

    #pragma unroll
    for (int jj = 0; jj < 8; ++jj) {
        float v0 = wa[jj * 3], v1 = wa[jj * 3 + 1], v2 = wa[jj * 3 + 2];
        float lsum = v0 + v1 + v2;
        float lsq  = fmaf(v0, v0, fmaf(v1, v1, v2 * v2));
        #pragma unroll
        for (int off = 32; off; off >>= 1) {
            lsum += __shfl_down(lsum, off, 64);
            lsq  += __shfl_down(lsq,  off, 64);
        }
        if (lane == 0) {
            atomicAdd(&gnsum[b2 * 32 + q * 8 + jj], lsum);
            atomicAdd(&gnsq [b2 * 32 + q * 8 + jj], lsq);
        }
    }
}

// ---- kC2: finalize GroupNorm stats ----
__global__ __launch_bounds__(256) void kC2_gn(
    const float* __restrict__ gnsum, const float* __restrict__ gnsq,
    float* __restrict__ gnmean, float* __restrict__ gnrstd)
{
    int idx = blockIdx.x * 256 + threadIdx.x;
    const float inv = 1.f / 12288.f;
    float mu  = gnsum[idx] * inv;
    float var = fmaf(gnsq[idx], inv, -mu * mu);
    gnmean[idx] = mu;
    gnrstd[idx] = rsqrtf(fmaxf(var, 0.f) + EPSV);
}

// ---- kD: agg = SiLU(BN2(sum_k GN(wd)*unfold(v))) -> d_out, + gap ----
// Block = (bi, c1, 512-px strip); loops all 8 frames, 4 channels of c1.
// v rolled through registers (read once); wd read once. Thread = 2 px.
__global__ __launch_bounds__(256, 8) void kD_agg(
    const float* __restrict__ wd, const float* __restrict__ v,
    const float* __restrict__ gnmean, const float* __restrict__ gnrstd,
    const float* __restrict__ gng, const float* __restrict__ gnb,
    const float* __restrict__ g, const float* __restrict__ bb,
    const float* __restrict__ m, const float* __restrict__ vr,
    float* __restrict__ out, float* __restrict__ gap)
{
    int blk   = blockIdx.x;
    int strip = blk & 7;
    int c1    = (blk >> 3) & 31;
    int bi    = blk >> 8;            // grid = 4*32*8 = 1024
    int px0   = strip * 512 + threadIdx.x * 2;

    float sch[4], tch[4], gl[4];
    #pragma unroll
    for (int ch = 0; ch < 4; ++ch) {
        int c = c1 * 4 + ch;
        float s = g[c] * rsqrtf(vr[c] + EPSV);
        sch[ch] = s; tch[ch] = bb[c] - m[c] * s; gl[ch] = 0.f;
    }
    float gg[3], gb[3];
    #pragma unroll
    for (int k = 0; k < 3; ++k) { gg[k] = gng[c1 * 3 + k]; gb[k] = gnb[c1 * 3 + k]; }

    // rolling v window: slot k holds frame (ni + k - 1)
    float2 vreg[4][3];
    #pragma unroll
    for (int ch = 0; ch < 4; ++ch) {
        vreg[ch][0] = make_float2(0.f, 0.f);
        vreg[ch][1] = *(const float2*)(v + ((bi * 8 + 0) * 128 + c1 * 4 + ch) * 4096 + px0);
        vreg[ch][2] = *(const float2*)(v + ((bi * 8 + 1) * 128 + c1 * 4 + ch) * 4096 + px0);
    }

    for (int ni = 0; ni < 8; ++ni) {
        int b2 = bi * 8 + ni;
        float mu = gnmean[b2 * 32 + c1], rs = gnrstd[b2 * 32 + c1];
        float2 wn[3];
        #pragma unroll
        for (int k = 0; k < 3; ++k) {
            int nf = ni + k - 1;
            if (nf >= 0 && nf < 8) {
                const float2 wv = *(const float2*)(wd + (b2 * 96 + c1 * 3 + k) * 4096 + px0);
                wn[k].x = fmaf((wv.x - mu) * rs, gg[k], gb[k]);
                wn[k].y = fmaf((wv.y - mu) * rs, gg[k], gb[k]);
            } else {
                wn[k] = make_float2(0.f, 0.f);
            }
        }
        #pragma unroll
        for (int ch = 0; ch < 4; ++ch) {
            float a0 = 0.f, a1 = 0.f;
            #pragma unroll
            for (int k = 0; k < 3; ++k) {
                a0 = fmaf(wn[k].x, vreg[ch][k].x, a0);
                a1 = fmaf(wn[k].y, vreg[ch][k].y, a1);
            }
            float y0 = fmaf(a0, sch[ch], tch[ch]);
            float y1 = fmaf(a1, sch[ch], tch[ch]);
            float2 r;
            r.x = y0 / (1.f + __expf(-y0));
            r.y = y1 / (1.f + __expf(-y1));
            *(float2*)(out + (b2 * 128 + c1 * 4 + ch) * 4096 + px0) = r;
            gl[ch] += r.x + r.y;
        }
        // shift window, load frame ni+2
        if (ni < 7) {
            #pragma unroll
            for (int ch = 0; ch < 4; ++ch) {
                vreg[ch][0] = vreg[ch][1];
                vreg[ch][1] = vreg[ch][2];
                if (ni + 2 < 8)
                    vreg[ch][2] = *(const float2*)(v + ((bi * 8 + ni + 2) * 128 + c1 * 4 + ch) * 4096 + px0);
            }
        }
    }

    // block-reduce the 4 per-channel gap partials
    __shared__ float sm[4][4];
    int lane = threadIdx.x & 63, wid = threadIdx.x >> 6;
    #pragma unroll
    for (int ch = 0; ch < 4; ++ch) {
        float s = gl[ch];
        #pragma unroll
        for (int off = 32; off; off >>= 1) s += __shfl_down(s, off, 64);
        if (lane == 0) sm[ch][wid] = s;
    }
    __syncthreads();
    if (threadIdx.x < 4) {
        float* sr = sm[threadIdx.x];
        atomicAdd(&gap[bi * 128 + c1 * 4 + threadIdx.x], sr[0] + sr[1] + sr[2] + sr[3]);
    }
}

// ---- kE1: a = ReLU(BNvec(gap/32768 @ w1^T + b1)) ----
__global__ __launch_bounds__(256) void kE1_a(
    const float* __restrict__ gap,
    const float* __restrict__ w1, const float* __restrict__ b1,
    const float* __restrict__ g, const float* __restrict__ bb,
    const float* __restrict__ m, const float* __restrict__ vr,
    float* __restrict__ a_buf)
{
    int idx = blockIdx.x * 256 + threadIdx.x;
    int bi = idx >> 7, oc = idx & 127;
    float acc = b1[oc];
    const float* gp = gap + bi * 128;
    const float* wp = w1 + oc * 128;
    for (int c = 0; c < 128; c += 4) {
        const float4 w4 = *(const float4*)(wp + c);
        acc = fmaf(gp[c + 0] * (1.f / 32768.f), w4.x, acc);
        acc = fmaf(gp[c + 1] * (1.f / 32768.f), w4.y, acc);
        acc = fmaf(gp[c + 2] * (1.f / 32768.f), w4.z, acc);
        acc = fmaf(gp[c + 3] * (1.f / 32768.f), w4.w, acc);
    }
    float s = g[oc] * rsqrtf(vr[oc] + EPSV);
    a_buf[bi * 128 + oc] = fmaxf(fmaf(acc, s, bb[oc] - m[oc] * s), 0.f);
}

// ---- kE2: attn = softmax over radix-2 pairs ----
__global__ __launch_bounds__(256) void kE2_attn(
    const float* __restrict__ a_buf,
    const float* __restrict__ w2, const float* __restrict__ b2v,
    float* __restrict__ attn)
{
    int idx = blockIdx.x * 256 + threadIdx.x;
    int bi = idx >> 7, cc = idx & 127;
    float l0 = b2v[cc * 2], l1 = b2v[cc * 2 + 1];
    const float* ap  = a_buf + bi * 128;
    const float* w0p = w2 + (cc * 2) * 128;
    const float* w1p = w2 + (cc * 2 + 1) * 128;
    for (int j = 0; j < 128; j += 4) {
        const float4 wa4 = *(const float4*)(w0p + j);
        const float4 wb4 = *(const float4*)(w1p + j);
        l0 = fmaf(ap[j + 0], wa4.x, l0); l1 = fmaf(ap[j + 0], wb4.x, l1);
        l0 = fmaf(ap[j + 1], wa4.y, l0); l1 = fmaf(ap[j + 1], wb4.y, l1);
        l0 = fmaf(ap[j + 2], wa4.z, l0); l1 = fmaf(ap[j + 2], wb4.z, l1);
        l0 = fmaf(ap[j + 3], wa4.w, l0); l1 = fmaf(ap[j + 3], wb4.w, l1);
    }
    float mx = fmaxf(l0, l1);
    float e0 = __expf(l0 - mx), e1 = __expf(l1 - mx);
    float inv = 1.f / (e0 + e1);
    attn[bi * 256 + cc * 2]     = e0 * inv;
    attn[bi * 256 + cc * 2 + 1] = e1 * inv;
}

// ---- kF: out = attn0*agg + attn1*k2d; thread = 4 px ----
__global__ __launch_bounds__(256, 8) void kF_out(
    float* __restrict__ out, const float* __restrict__ k2d,
    const float* __restrict__ attn)
{
    int blk   = blockIdx.x;
    int strip = blk & 3;
    int c     = (blk >> 2) & 127;
    int b2    = blk >> 9;
    int bi    = b2 >> 3;
    float a0 = attn[bi * 256 + c * 2];
    float a1 = attn[bi * 256 + c * 2 + 1];
    int idx = (b2 * 128 + c) * 4096 + strip * 1024 + threadIdx.x * 4;
    float4 o4 = *(const float4*)(out + idx);
    float4 k4 = *(const float4*)(k2d + idx);
    float4 r;
    r.x = fmaf(a0, o4.x, a1 * k4.x);
    r.y = fmaf(a0, o4.y, a1 * k4.y);
    r.z = fmaf(a0, o4.z, a1 * k4.z);
    r.w = fmaf(a0, o4.w, a1 * k4.w);
    *(float4*)(out + idx) = r;
}

extern "C" void kernel_launch(void* const* d_in, const int* in_sizes, int n_in,
                              void* d_out, int out_size, void* d_ws, size_t ws_size,
                              hipStream_t stream)
{
    const float* x      = (const float*)d_in[0];
    const float* w_key  = (const float*)d_in[1];
    const float* bnk_g  = (const float*)d_in[2];
    const float* bnk_b  = (const float*)d_in[3];
    const float* bnk_m  = (const float*)d_in[4];
    const float* bnk_v  = (const float*)d_in[5];
    const float* w_e1   = (const float*)d_in[6];
    const float* bne_g  = (const float*)d_in[7];
    const float* bne_b  = (const float*)d_in[8];
    const float* bne_m  = (const float*)d_in[9];
    const float* bne_v  = (const float*)d_in[10];
    const float* w_e2   = (const float*)d_in[11];
    const float* b_e2   = (const float*)d_in[12];
    const float* gn_g   = (const float*)d_in[13];
    const float* gn_b   = (const float*)d_in[14];
    const float* w_1x1  = (const float*)d_in[15];
    const float* bn1_g  = (const float*)d_in[16];
    const float* bn1_b  = (const float*)d_in[17];
    const float* bn1_m  = (const float*)d_in[18];
    const float* bn1_v  = (const float*)d_in[19];
    const float* bn2_g  = (const float*)d_in[20];
    const float* bn2_b  = (const float*)d_in[21];
    const float* bn2_m  = (const float*)d_in[22];
    const float* bn2_v  = (const float*)d_in[23];
    const float* w_se1  = (const float*)d_in[24];
    const float* b_se1  = (const float*)d_in[25];
    const float* bnse_g = (const float*)d_in[26];
    const float* bnse_b = (const float*)d_in[27];
    const float* bnse_m = (const float*)d_in[28];
    const float* bnse_v = (const float*)d_in[29];
    const float* w_se2  = (const float*)d_in[30];
    const float* b_se2  = (const float*)d_in[31];

    float* ws    = (float*)d_ws;
    float* k2d   = ws;
    float* v     = ws + 16777216;
    float* wd    = ws + 33554432;
    float* st    = ws + 46137344;
    float* gnsum  = st;
    float* gnsq   = st + 1024;
    float* gap    = st + 2048;
    float* gnmean = st + 2560;
    float* gnrstd = st + 3584;
    float* attn   = st + 4608;
    float* a_buf  = st;            // aliases gnsum (dead after kC2)

    hipMemsetAsync(gnsum, 0, 2560 * sizeof(float), stream);

    kA_key<<<1024, 256, 0, stream>>>(x, w_key, bnk_g, bnk_b, bnk_m, bnk_v, k2d, gap);
    kB_val<<<1024, 256, 0, stream>>>(x, w_1x1, bn1_g, bn1_b, bn1_m, bn1_v, v);
    kC_wd<<<2048, 256, 0, stream>>>(x, k2d, w_e1, bne_g, bne_b, bne_m, bne_v,
                                    w_e2, b_e2, wd, gnsum, gnsq);
    kC2_gn<<<4, 256, 0, stream>>>(gnsum, gnsq, gnmean, gnrstd);
    kD_agg<<<1024, 256, 0, stream>>>(wd, v, gnmean, gnrstd, gn_g, gn_b,
                                     bn2_g, bn2_b, bn2_m, bn2_v,
                                     (float*)d_out, gap);
    kE1_a<<<2, 256, 0, stream>>>(gap, w_se1, b_se1, bnse_g, bnse_b, bnse_m, bnse_v, a_buf);
    kE2_attn<<<2, 256, 0, stream>>>(a_buf, w_se2, b_se2, attn);
    kF_out<<<16384, 256, 0, stream>>>((float*)d_out, k2d, attn);
}